// Round 5
// baseline (394.994 us; speedup 1.0000x reference)
//
#include <hip/hip_runtime.h>
#include <hip/hip_fp16.h>

// x [4,64,256,256] f32, flow [4,2,256,256] f32 -> out [4,320,256,256] f32
#define BB 4
#define CC 64
#define HH 256
#define WW 256
#define HWHW (HH * WW)

typedef float vf4 __attribute__((ext_vector_type(4)));  // NT-able float4

union H4 {
    __half2 h2[2];
    uint2 u;
};

// Load 4 fp16 channels (8 B) and widen to f32.
__device__ __forceinline__ float4 ld4h(const __half* p) {
    const H4 r = *(const H4*)p;
    const float2 a = __half22float2(r.h2[0]);
    const float2 b = __half22float2(r.h2[1]);
    return make_float4(a.x, a.y, b.x, b.y);
}

// XOR swizzle for the unpadded sm tile: k = c>>2 (0..15).
// Bits 2..5 only -> preserves float4 alignment; write-side 2-way (free),
// read-side conflict-free.
__device__ __forceinline__ int smz(int k, int px) {
    return px ^ (((k & 7) << 3) | ((k >> 3) << 2));
}

// Kernel A: transpose+downconvert x [B,C,HW] f32 -> xt [B,HW,C] fp16 so
// gather taps are coalesced AND half-width (one 128B line per tap).
__global__ __launch_bounds__(256) void transpose_xk(const float* __restrict__ x,
                                                    __half* __restrict__ xt) {
    __shared__ float tile[64][65];
    const int b = blockIdx.y;
    const int hw0 = blockIdx.x << 6;
    const int t = threadIdx.x;
    const float* xb = x + (size_t)b * CC * HWHW;

    const int cq = t >> 4;          // 0..15
    const int px4 = (t & 15) << 2;  // 0,4,...,60
#pragma unroll
    for (int k = 0; k < 4; ++k) {
        const int c = cq + (k << 4);
        const vf4 v = __builtin_nontemporal_load(
            (const vf4*)&xb[(size_t)c * HWHW + hw0 + px4]);
        tile[c][px4 + 0] = v.x;
        tile[c][px4 + 1] = v.y;
        tile[c][px4 + 2] = v.z;
        tile[c][px4 + 3] = v.w;
    }
    __syncthreads();
    __half* xtb = xt + ((size_t)b * HWHW << 6);
    const int hwq = t >> 4;         // 0..15
    const int c4 = (t & 15) << 2;   // 0,4,...,60
#pragma unroll
    for (int k = 0; k < 4; ++k) {
        const int hw = hwq + (k << 4);
        H4 h;
        h.h2[0] = __floats2half2_rn(tile[c4 + 0][hw], tile[c4 + 1][hw]);
        h.h2[1] = __floats2half2_rn(tile[c4 + 2][hw], tile[c4 + 3][hw]);
        *(uint2*)&xtb[((size_t)(hw0 + hw) << 6) + c4] = h.u;  // 128B/16 lanes
    }
}

// Kernel B: fused 5-variant OBMC warp.
// Round-5: single barrier per g via parity-double-buffered swizzled sm
// (no pad), dOff packed to int2 (base + {dy|dx}), float4 NT store phase.
// LDS = 2*16384 + 2560 + 5120 = 40448 B -> exactly 4 blocks/CU, same
// occupancy as before but half the barriers and 1/4 the store instrs.
__global__ __launch_bounds__(256) void obmc_kernel(const __half* __restrict__ xt,
                                                   const float* __restrict__ flow,
                                                   float* __restrict__ out) {
    __shared__ int2 dOffp[5][64];     // {base<<6, (dy16<<16)|dx16} half-index
    __shared__ float4 dW[5][64];      // validity-masked bilinear weights
    __shared__ float sm[2][64][64];   // parity-dbuf, XOR-swizzled (no pad)

    // bijective XCD swizzle (4096 % 8 == 0)
    const int bid = ((blockIdx.x & 7) << 9) + (blockIdx.x >> 3);
    const int tx0 = (bid & 3) << 6;
    const int y = (bid >> 2) & 255;
    const int b = bid >> 10;
    const int t = threadIdx.x;
    const int wv = t >> 6;
    const int lane = t & 63;
    const int sp = lane >> 4;
    const int kk = lane & 15;        // c-quad index for gather/FMA phase
    const int c4 = kk << 2;

    const __half* xtb = xt + ((size_t)b * HWHW << 6);
    const float* fb = flow + (size_t)b * 2 * HWHW;
    float* ob = out + (size_t)b * 5 * CC * HWHW + (size_t)y * WW + tx0;

    const int oys[5] = {0, 1, 0, -1, 0};
    const int oxs[5] = {0, 0, 1, 0, -1};

    // ---- pre-phase: 320 descriptors by 256 threads ----
    for (int idx = t; idx < 320; idx += 256) {
        const int g = idx >> 6, px = idx & 63;
        const int sy = y + oys[g];
        const int sx = tx0 + px + oxs[g];
        float fx = 0.f, fy = 0.f;
        if ((unsigned)sy < HH && (unsigned)sx < WW) {
            const int fo = sy * WW + sx;
            fx = fb[fo];
            fy = fb[HWHW + fo];
        }
        const float gx = (float)(tx0 + px) + fx;
        const float gy = (float)y + fy;
        const float x0f = floorf(gx);
        const float y0f = floorf(gy);
        const float fwx = gx - x0f;
        const float fwy = gy - y0f;
        const int ix0 = (int)x0f, iy0 = (int)y0f;
        const int ix1 = ix0 + 1, iy1 = iy0 + 1;
        const float vx0 = ((unsigned)ix0 < WW) ? 1.f : 0.f;
        const float vx1 = ((unsigned)ix1 < WW) ? 1.f : 0.f;
        const float vy0 = ((unsigned)iy0 < HH) ? 1.f : 0.f;
        const float vy1 = ((unsigned)iy1 < HH) ? 1.f : 0.f;
        const int xc0 = min(max(ix0, 0), WW - 1);
        const int xc1 = min(max(ix1, 0), WW - 1);
        const int yc0 = min(max(iy0, 0), HH - 1);
        const int yc1 = min(max(iy1, 0), HH - 1);
        // base tap offset (half-index, <<6 for 64 channels); deltas are
        // {0,64} (x) and {0,16384} (y), packed 16|16.
        const int base = ((yc0 * WW + xc0) << 6);
        const int dx = (xc1 - xc0) << 6;
        const int dyv = (yc1 - yc0) << 14;
        dOffp[g][px] = make_int2(base, (dyv << 16) | dx);
        dW[g][px] = make_float4((1.f - fwx) * (1.f - fwy) * vx0 * vy0,
                                fwx * (1.f - fwy) * vx1 * vy0,
                                (1.f - fwx) * fwy * vx0 * vy1,
                                fwx * fwy * vx1 * vy1);
    }
    __syncthreads();

    for (int g = 0; g < 5; ++g) {
        const int p = g & 1;
        float4 acc[4];
#pragma unroll
        for (int i = 0; i < 4; ++i) {
            const int px = (wv << 4) + (i << 2) + sp;
            const int2 o = dOffp[g][px];    // broadcast ds_read_b64
            const float4 w = dW[g][px];     // broadcast ds_read_b128
            const int o0 = o.x + c4;
            const int dx = o.y & 0xffff;
            const int dyv = ((unsigned)o.y) >> 16;
            const float4 v0 = ld4h(xtb + o0);
            const float4 v1 = ld4h(xtb + o0 + dx);
            const float4 v2 = ld4h(xtb + o0 + dyv);
            const float4 v3 = ld4h(xtb + o0 + dyv + dx);
            float4 a;
            a.x = w.x * v0.x; a.y = w.x * v0.y; a.z = w.x * v0.z; a.w = w.x * v0.w;
            a.x = fmaf(w.y, v1.x, a.x); a.y = fmaf(w.y, v1.y, a.y);
            a.z = fmaf(w.y, v1.z, a.z); a.w = fmaf(w.y, v1.w, a.w);
            a.x = fmaf(w.z, v2.x, a.x); a.y = fmaf(w.z, v2.y, a.y);
            a.z = fmaf(w.z, v2.z, a.z); a.w = fmaf(w.z, v2.w, a.w);
            a.x = fmaf(w.w, v3.x, a.x); a.y = fmaf(w.w, v3.y, a.y);
            a.z = fmaf(w.w, v3.z, a.z); a.w = fmaf(w.w, v3.w, a.w);
            acc[i] = a;
        }
#pragma unroll
        for (int i = 0; i < 4; ++i) {
            const int px = (wv << 4) + (i << 2) + sp;
            const int zp = smz(kk, px);
            sm[p][c4 + 0][zp] = acc[i].x;
            sm[p][c4 + 1][zp] = acc[i].y;
            sm[p][c4 + 2][zp] = acc[i].z;
            sm[p][c4 + 3][zp] = acc[i].w;
        }
        __syncthreads();   // single barrier per g (parity dbuf makes the
                           // second one redundant: a wave's stores finish
                           // before it reaches the NEXT barrier)
#pragma unroll
        for (int m = 0; m < 4; ++m) {
            const int c = (wv << 4) + (m << 2) + sp;
            const int px4 = kk << 2;
            const vf4 v = *(const vf4*)&sm[p][c][smz(c >> 2, px4)];
            __builtin_nontemporal_store(
                v, (vf4*)&ob[(size_t)(g * CC + c) * HWHW + px4]);
        }
    }
}

extern "C" void kernel_launch(void* const* d_in, const int* in_sizes, int n_in,
                              void* d_out, int out_size, void* d_ws, size_t ws_size,
                              hipStream_t stream) {
    const float* x = (const float*)d_in[0];
    const float* flow = (const float*)d_in[1];
    float* out = (float*)d_out;
    __half* xt = (__half*)d_ws;  // 32 MiB scratch (fp16)

    transpose_xk<<<dim3(HWHW / 64, BB), 256, 0, stream>>>(x, xt);
    obmc_kernel<<<BB * HH * (WW / 64), 256, 0, stream>>>(xt, flow, out);
}